// Round 14
// baseline (268.321 us; speedup 1.0000x reference)
//
#include <hip/hip_runtime.h>

typedef short bf16x8 __attribute__((ext_vector_type(8)));
typedef float f32x4 __attribute__((ext_vector_type(4)));
typedef int   int4v  __attribute__((ext_vector_type(4)));

#define MFMA16(a, b, c) __builtin_amdgcn_mfma_f32_16x16x32_bf16((a), (b), (c), 0, 0, 0)

static constexpr int T_LEN = 512;
static constexpr int F_DIM = 64;
static constexpr int NB    = 16;   // batch rows per block -> 256 blocks -> 1 block/CU
static constexpr float C1  = 2.885390081777927f;  // 2*log2(e)

// exact RNE (one-time weight conversion only)
__device__ __forceinline__ unsigned short brne(float f) {
  unsigned u = __float_as_uint(f);
  return (unsigned short)((u + 0x7fffu + ((u >> 16) & 1u)) >> 16);
}

// round-half-up fp32->bf16 (2 VALU ops; validated rounds 4-13)
__device__ __forceinline__ unsigned short rhu(float f) {
  return (unsigned short)((__float_as_uint(f) + 0x8000u) >> 16);
}

// v_cvt_pk_bf16_f32: packs 2 fp32 -> 2 bf16 (RNE) in one dword. No builtin.
__device__ __forceinline__ int cvtpk(float lo, float hi) {
  int r;
  asm("v_cvt_pk_bf16_f32 %0, %1, %2" : "=v"(r) : "v"(lo), "v"(hi));
  return r;
}

__device__ __forceinline__ bf16x8 cvt8(const float4 &a, const float4 &b) {
  int4v d = {cvtpk(a.x, a.y), cvtpk(a.z, a.w), cvtpk(b.x, b.y), cvtpk(b.z, b.w)};
  union { int4v i; bf16x8 h; } u;
  u.i = d;
  return u.h;
}

// tanh(s + bias) with bias pre-folded: c2 = C1*bias
__device__ __forceinline__ float tanh_fold(float s, float c2) {
  float e  = __builtin_amdgcn_exp2f(__builtin_fmaf(s, C1, c2));
  float rc = __builtin_amdgcn_rcpf(e + 1.0f);
  return __builtin_fmaf(-2.0f, rc, 1.0f);
}

// Raw workgroup barrier: orders LDS writes (lgkmcnt) but leaves global x
// prefetch loads (vmcnt) in flight.  sched_barrier(0) is mandatory: LLVM's
// s_barrier is NOT a memory fence and will hoist post-barrier ds_reads
// (round-9 NaN lesson).  Validated rounds 8, 13.
__device__ __forceinline__ void bar() {
  asm volatile("s_waitcnt lgkmcnt(0)" ::: "memory");
  __builtin_amdgcn_s_barrier();
  __builtin_amdgcn_sched_barrier(0);
}

// One RNN step (m-cell then p-cell).  NB=16: zero MFMA row-duplication.
// CHAIN-SHORTENED (round 14): (1) each accumulator chain ends with the
// freshly-LDS-read operand, so the post-barrier dependency is read + ONE
// MFMA; (2) the p-cell's 4 independent MFMAs (x,p_old) are hoisted above
// bar1 (round-8-validated pattern), overlapping the m-epilogue's tanh on
// the MFMA pipe.  m_old carried in registers (round-12-validated).
template<bool FIN>
__device__ __forceinline__ void step_cells(
    int arow, int g8, int j, int rowb,
    const bf16x8 &x0, const bf16x8 &x1,
    bf16x8 &mo0, bf16x8 &mo1,
    const bf16x8 (&Bm)[6], const bf16x8 (&Bp)[6],
    float c2m, float c2p, const f32x4 &Z,
    unsigned short (*sm)[72],
    unsigned short (*sp_c)[72], unsigned short (*sp_p)[72],
    float (*mfin)[68], float (*pfin)[68])
{
  // p_old fragments — issue reads first (entry point is just after the
  // previous step's trailing bar, so sp_p is stable and visible)
  bf16x8 p0 = *(const bf16x8 *)&sp_p[arow][g8];
  bf16x8 p1 = *(const bf16x8 *)&sp_p[arow][32 + g8];

  // ---------------- metrics cell: in = [x | p_old | m_old(carried)]
  // chains ordered x -> mo(reg) -> p(read-last)
  f32x4 a0 = MFMA16(x0, Bm[0], Z);
  f32x4 a1 = MFMA16(x1, Bm[1], Z);
  a0 = MFMA16(mo0, Bm[4], a0);
  a1 = MFMA16(mo1, Bm[5], a1);
  a0 = MFMA16(p0, Bm[2], a0);       // first MFMA needing the ds_read
  a1 = MFMA16(p1, Bm[3], a1);
  // p-cell independent part (x, p_old) hoisted above bar1 — its MFMA-pipe
  // execution overlaps the m-epilogue VALU below (round-8 pattern)
  f32x4 b0 = MFMA16(x0, Bp[0], Z);
  f32x4 b1 = MFMA16(x1, Bp[1], Z);
  b0 = MFMA16(p0, Bp[4], b0);
  b1 = MFMA16(p1, Bp[5], b1);
  // m epilogue
#pragma unroll
  for (int r = 0; r < 4; ++r) {
    float tv = tanh_fold(a0[r] + a1[r], c2m);
    sm[rowb + r][j] = rhu(tv);
    if (FIN) mfin[rowb + r][j] = tv;
  }
  bar();   // m_new visible to all waves
  // ---------------- price cell: m_new-dependent tail (read + ONE MFMA)
  {
    bf16x8 n0 = *(const bf16x8 *)&sm[arow][g8];
    bf16x8 n1 = *(const bf16x8 *)&sm[arow][32 + g8];
    b0 = MFMA16(n0, Bp[2], b0);
    b1 = MFMA16(n1, Bp[3], b1);
    mo0 = n0;   // carry m(t) -> next step's m_old (round-12 pattern)
    mo1 = n1;
#pragma unroll
    for (int r = 0; r < 4; ++r) {
      float tv = tanh_fold(b0[r] + b1[r], c2p);
      sp_c[rowb + r][j] = rhu(tv);
      if (FIN) pfin[rowb + r][j] = tv;
    }
  }
  bar();   // p_new visible; prev p-buffer free next step
}

__global__ __launch_bounds__(256, 1)
void mr_rnn_kernel(const float *__restrict__ x,
                   const float *__restrict__ mWih, const float *__restrict__ mWhh,
                   const float *__restrict__ mbih, const float *__restrict__ mbhh,
                   const float *__restrict__ pWih, const float *__restrict__ pWhh,
                   const float *__restrict__ pbih, const float *__restrict__ pbhh,
                   const float *__restrict__ plW,  const float *__restrict__ plb,
                   const float *__restrict__ mlW,  const float *__restrict__ mlb,
                   float *__restrict__ out, int B)
{
  __shared__ __align__(16) unsigned short sm[NB][72];      // single m buffer
  __shared__ __align__(16) unsigned short sp[2][NB][72];   // p double buffer
  __shared__ __align__(16) float s_mfin[NB][68], s_pfin[NB][68];

  const int tid  = threadIdx.x;
  const int lane = tid & 63;
  const int q    = tid >> 6;        // wave id -> output col tile
  const int l15  = lane & 15;
  const int arow = l15;             // batch row within block (all 16 distinct)
  const int g    = lane >> 4;       // k-group
  const int j    = q * 16 + l15;    // output feature owned by this lane's wave
  const int b0   = blockIdx.x * NB;
  const int g8   = g * 8;
  const int rowb = g * 4;           // C rows 4g..4g+3 owned by this lane

  // ---- register-resident bf16 weight B-fragments: B[k][j] = W[j][k]
  bf16x8 Bm[6], Bp[6];
#pragma unroll
  for (int kt = 0; kt < 6; ++kt) {
    const int k0 = kt * 32 + g8;
#pragma unroll
    for (int i = 0; i < 8; ++i) {
      const int k = k0 + i;
      float wm = (k < 128) ? mWih[j * 128 + k] : mWhh[j * 64 + (k - 128)];
      float wp = (k < 128) ? pWih[j * 128 + k] : pWhh[j * 64 + (k - 128)];
      Bm[kt][i] = (short)brne(wm);
      Bp[kt][i] = (short)brne(wp);
    }
  }
  const float c2m = C1 * (mbih[j] + mbhh[j]);   // bias folded into exp2 arg
  const float c2p = C1 * (pbih[j] + pbhh[j]);
  const f32x4 Z = {0.f, 0.f, 0.f, 0.f};         // hoisted accumulator seed

  // ---- zero the t=-1 p-state buffer (parity index 1); m(-1)=0 is carried
  for (int idx = tid; idx < NB * 72; idx += 256) {
    const int bb = idx / 72, kk = idx % 72;
    sp[1][bb][kk] = 0;
  }
  bf16x8 mo0 = {0, 0, 0, 0, 0, 0, 0, 0};   // m(-1) = 0 (bf16 zero bits)
  bf16x8 mo1 = {0, 0, 0, 0, 0, 0, 0, 0};

  // ---- x stream: lane covers batch b0+arow, features [g8,g8+8) and
  //      [32+g8,32+g8+8), EVERY step.  2-deep named-register prefetch (Q/R).
  const float *pxl = x + (size_t)(b0 + arow) * T_LEN * F_DIM + g8;
  float4 Q0 = *(const float4 *)(pxl);
  float4 Q1 = *(const float4 *)(pxl + 4);
  float4 Q2 = *(const float4 *)(pxl + 32);
  float4 Q3 = *(const float4 *)(pxl + 36);
  bf16x8 x0 = cvt8(Q0, Q1);
  bf16x8 x1 = cvt8(Q2, Q3);
  float4 R0 = *(const float4 *)(pxl + F_DIM);
  float4 R1 = *(const float4 *)(pxl + F_DIM + 4);
  float4 R2 = *(const float4 *)(pxl + F_DIM + 32);
  float4 R3 = *(const float4 *)(pxl + F_DIM + 36);
  __syncthreads();   // zero-init visible (one full drain, outside the loop)

  // invariant at loop top: x0/x1 = x(t) converted, R = raw x(t+1)
#pragma unroll 1
  for (int t = 0; t < T_LEN - 2; t += 2) {
    // prefetch raw x(t+2) into Q (stays in flight across bar()s)
    Q0 = *(const float4 *)(pxl + 2 * F_DIM);
    Q1 = *(const float4 *)(pxl + 2 * F_DIM + 4);
    Q2 = *(const float4 *)(pxl + 2 * F_DIM + 32);
    Q3 = *(const float4 *)(pxl + 2 * F_DIM + 36);
    // step t (even): p cur parity 0, prev 1
    step_cells<false>(arow, g8, j, rowb, x0, x1, mo0, mo1,
                      Bm, Bp, c2m, c2p, Z,
                      sm, sp[0], sp[1], s_mfin, s_pfin);
    x0 = cvt8(R0, R1);   // x(t+1)
    x1 = cvt8(R2, R3);
    // prefetch raw x(t+3) into R
    R0 = *(const float4 *)(pxl + 3 * F_DIM);
    R1 = *(const float4 *)(pxl + 3 * F_DIM + 4);
    R2 = *(const float4 *)(pxl + 3 * F_DIM + 32);
    R3 = *(const float4 *)(pxl + 3 * F_DIM + 36);
    // step t+1 (odd): p cur parity 1, prev 0
    step_cells<false>(arow, g8, j, rowb, x0, x1, mo0, mo1,
                      Bm, Bp, c2m, c2p, Z,
                      sm, sp[1], sp[0], s_mfin, s_pfin);
    x0 = cvt8(Q0, Q1);   // x(t+2)
    x1 = cvt8(Q2, Q3);
    pxl += 2 * F_DIM;
  }
  // ---- tail: steps 510, 511 (x0=x(510), R=raw x(511); 511 writes finals)
  step_cells<false>(arow, g8, j, rowb, x0, x1, mo0, mo1,
                    Bm, Bp, c2m, c2p, Z,
                    sm, sp[0], sp[1], s_mfin, s_pfin);
  x0 = cvt8(R0, R1);
  x1 = cvt8(R2, R3);
  step_cells<true>(arow, g8, j, rowb, x0, x1, mo0, mo1,
                   Bm, Bp, c2m, c2p, Z,
                   sm, sp[1], sp[0], s_mfin, s_pfin);
  __syncthreads();   // finals visible to head threads (full drain, once)

  // ---- heads
  if (tid < NB) {
    const int b = tid;
    float acc = plb[0];
#pragma unroll 1
    for (int k = 0; k < 64; ++k) acc += s_pfin[b][k] * plW[k];
    out[b0 + b] = acc;
  } else if (tid < NB + NB * 8) {
    const int r = tid - NB;
    const int b = r >> 3, e = r & 7;
    float acc = mlb[e];
#pragma unroll 1
    for (int k = 0; k < 64; ++k) acc += s_mfin[b][k] * mlW[e * 64 + k];
    out[(size_t)B + (size_t)(b0 + b) * 8 + e] = acc;
  }
}

extern "C" void kernel_launch(void* const* d_in, const int* in_sizes, int n_in,
                              void* d_out, int out_size, void* d_ws, size_t ws_size,
                              hipStream_t stream) {
  (void)n_in; (void)out_size; (void)d_ws; (void)ws_size;
  const float* x    = (const float*)d_in[0];
  const float* mWih = (const float*)d_in[1];
  const float* mWhh = (const float*)d_in[2];
  const float* mbih = (const float*)d_in[3];
  const float* mbhh = (const float*)d_in[4];
  const float* pWih = (const float*)d_in[5];
  const float* pWhh = (const float*)d_in[6];
  const float* pbih = (const float*)d_in[7];
  const float* pbhh = (const float*)d_in[8];
  const float* plW  = (const float*)d_in[9];
  const float* plb  = (const float*)d_in[10];
  const float* mlW  = (const float*)d_in[11];
  const float* mlb  = (const float*)d_in[12];
  const int B = in_sizes[0] / (T_LEN * F_DIM);
  const int nblk = B / NB;   // 256 blocks -> 1 block/CU, 16 valid rows/MFMA
  mr_rnn_kernel<<<dim3(nblk), dim3(256), 0, stream>>>(
      x, mWih, mWhh, mbih, mbhh, pWih, pWhh, pbih, pbhh,
      plW, plb, mlW, mlb, (float*)d_out, B);
}